// Round 5
// baseline (166.630 us; speedup 1.0000x reference)
//
#include <hip/hip_runtime.h>

#define BS      128
#define NF      4
#define NC      36
#define P_LO    1024
#define P_HI    16384
#define KNN     9
#define THREADS 256
#define TILE_P  256
#define NTILES  (P_HI / TILE_P)     // 64
#define LIST_OFF 64                 // ints; ws[0..35]=counts, ws[64+c*128+i]=sample ids
#define SCHED_OFF 36                // 9 ints = 36 packed bytes: rank -> class (LPT order)

// ---- pre-pass: bucket samples by class; also LPT schedule (count desc) ----
__global__ __launch_bounds__(128) void build_lists_kernel(
    const int* __restrict__ cls_ids, int* __restrict__ ws)
{
    __shared__ int cnt[NC];
    __shared__ int pk[9];
    const int t = threadIdx.x;
    if (t < NC) cnt[t] = 0;
    if (t >= 64 && t < 73) pk[t - 64] = 0;
    __syncthreads();
    if (t < BS) {
        int c = cls_ids[t];
        int pos = atomicAdd(&cnt[c], 1);
        ws[LIST_OFF + c * BS + pos] = t;
    }
    __syncthreads();
    if (t < NC) {
        int ct = cnt[t];
        ws[t] = ct;
        int r = 0;                       // rank by (count desc, idx asc) -> bijective
        for (int j = 0; j < NC; ++j) {
            int cj = cnt[j];
            r += (cj > ct) || (cj == ct && j < t);
        }
        atomicOr(&pk[r >> 2], t << ((r & 3) << 3));
    }
    __syncthreads();
    if (t < 9) ws[SCHED_OFF + t] = pk[t];
}

__device__ __forceinline__ void async_cp16(const void* g, void* l) {
    __builtin_amdgcn_global_load_lds(
        (const __attribute__((address_space(1))) void*)g,
        (__attribute__((address_space(3))) void*)l, 16, 0, 0);
}

// ---- main: block = (cls, tile); phase pipeline over (f, round) ----
// Bias is folded into a per-(f,thread) constant:
//   out = sum_k w_k * x[nb_k]  - sum_k w_k * bl[nb_k] + bh
// so the x planes are DMA'd RAW into LDS (global_load_lds, no VALU pass),
// double-buffered; each phase prefetches the next phase's planes and waits
// only vmcnt(4) (the 4 output stores stay in flight) -> no full drains,
// requests stay continuously outstanding across the block's lifetime.
__global__ __launch_bounds__(THREADS) void rect_up_kernel(
    const float* __restrict__ x,       // (BS, NF*P_LO)
    const int*   __restrict__ ws,      // counts + schedule + lists
    const int*   __restrict__ nbr,     // (P_HI, K)
    const float* __restrict__ wmap,    // (NC, NF, P_HI, K)
    const float* __restrict__ blo,     // (NC, NF, P_LO)
    const float* __restrict__ bhi,     // (NC, NF, P_HI)
    float*       __restrict__ out)     // (BS, NF, P_HI)
{
    __shared__ __align__(16) float ybuf[2][4][P_LO];   // 32768 B

    const int tile = blockIdx.x & (NTILES - 1);
    const int rank = blockIdx.x >> 6;
    const int cls  = (ws[SCHED_OFF + (rank >> 2)] >> ((rank & 3) << 3)) & 0xFF;
    const int n_b  = ws[cls];
    if (n_b == 0) return;              // uniform exit, before any barrier

    const int tid = threadIdx.x;
    const int p   = tile * TILE_P + tid;
    const int* list = ws + LIST_OFF + cls * BS;

    // round-0 ids (reused at every f boundary)
    const int i00 = list[0];
    const int i01 = (1 < n_b) ? list[1] : i00;
    const int i02 = (2 < n_b) ? list[2] : i00;
    const int i03 = (3 < n_b) ? list[3] : i00;

    int id0 = i00, id1 = i01, id2 = i02, id3 = i03;

    // DMA (f=0, r=0) raw x planes into buffer 0: 256 lanes x 16 B = one plane
    async_cp16(x + (size_t)(id0 * NF + 0) * P_LO + tid * 4, &ybuf[0][0][tid * 4]);
    async_cp16(x + (size_t)(id1 * NF + 0) * P_LO + tid * 4, &ybuf[0][1][tid * 4]);
    async_cp16(x + (size_t)(id2 * NF + 0) * P_LO + tid * 4, &ybuf[0][2][tid * 4]);
    async_cp16(x + (size_t)(id3 * NF + 0) * P_LO + tid * 4, &ybuf[0][3][tid * 4]);

    // per-thread rows for f=0 (contiguous 36 B/thread; wave = 2304 B span)
    float w[KNN]; int nb[KNN];
    {
        const float* wr = wmap + ((size_t)(cls * NF + 0) * P_HI + p) * KNN;
        const int*   ir = nbr + (size_t)p * KNN;
        #pragma unroll
        for (int k = 0; k < KNN; ++k) { w[k] = wr[k]; nb[k] = ir[k]; }
    }
    // fold bias: bhc = bh - sum_k w_k * bl[nb_k]
    float bhc = bhi[(size_t)(cls * NF + 0) * P_HI + p];
    {
        const float* blp = blo + (size_t)(cls * NF + 0) * P_LO;
        #pragma unroll
        for (int k = 0; k < KNN; ++k) bhc = fmaf(-w[k], blp[nb[k]], bhc);
    }

    // prologue-only full drain (DMA_0 definitely landed), then barrier
    asm volatile("s_waitcnt vmcnt(0) lgkmcnt(0)" ::: "memory");
    __builtin_amdgcn_s_barrier();

    const int R = (n_b + 3) >> 2;      // rounds of 4 samples per f
    int cur = 0;

    float wn[KNN], blg[KNN], bhn;

    for (int f = 0; f < NF; ++f) {
        for (int r = 0; r < R; ++r) {
            const bool fb   = (r == R - 1) && (f < NF - 1);   // f-boundary phase
            const bool last = (r == R - 1) && (f == NF - 1);

            // next phase's sample ids (uniform -> scalar loads)
            int n0 = id0, n1 = id1, n2 = id2, n3 = id3, nf = f;
            if (fb) { n0 = i00; n1 = i01; n2 = i02; n3 = i03; nf = f + 1; }
            else if (r + 1 < R) {
                const int s = 4 * (r + 1);
                n0 = list[s];
                n1 = (s + 1 < n_b) ? list[s + 1] : n0;
                n2 = (s + 2 < n_b) ? list[s + 2] : n0;
                n3 = (s + 3 < n_b) ? list[s + 3] : n0;
            }

            // 1. prefetch next phase's planes into the dead buffer
            if (!last) {
                float* dst = &ybuf[cur ^ 1][0][0];
                async_cp16(x + (size_t)(n0 * NF + nf) * P_LO + tid * 4, dst + 0 * P_LO + tid * 4);
                async_cp16(x + (size_t)(n1 * NF + nf) * P_LO + tid * 4, dst + 1 * P_LO + tid * 4);
                async_cp16(x + (size_t)(n2 * NF + nf) * P_LO + tid * 4, dst + 2 * P_LO + tid * 4);
                async_cp16(x + (size_t)(n3 * NF + nf) * P_LO + tid * 4, dst + 3 * P_LO + tid * 4);
                // pin the DMA group: the >=4 stores below must stay AFTER it,
                // so vmcnt(4) at phase end proves the DMAs have retired.
                __builtin_amdgcn_sched_barrier(0);
            }

            // 2. f-boundary: issue next-f rows now; consumed at phase end/next phase
            if (fb) {
                const float* wrn = wmap + ((size_t)(cls * NF + nf) * P_HI + p) * KNN;
                #pragma unroll
                for (int k = 0; k < KNN; ++k) wn[k] = wrn[k];
                bhn = bhi[(size_t)(cls * NF + nf) * P_HI + p];
                const float* blpn = blo + (size_t)(cls * NF + nf) * P_LO;
                #pragma unroll
                for (int k = 0; k < KNN; ++k) blg[k] = blpn[nb[k]];
            }

            // 3. gather: 36 ds_read_b32; 4 lanes/address = broadcast (conflict-free)
            const float* yb = &ybuf[cur][0][0];
            float a0 = 0.f, a1 = 0.f, a2 = 0.f, a3 = 0.f;
            #pragma unroll
            for (int k = 0; k < KNN; ++k) {
                const int o = nb[k];
                a0 = fmaf(w[k], yb[o], a0);
                a1 = fmaf(w[k], yb[o + P_LO], a1);
                a2 = fmaf(w[k], yb[o + 2 * P_LO], a2);
                a3 = fmaf(w[k], yb[o + 3 * P_LO], a3);
            }

            // 4. unconditional stores (clamped duplicates write identical values)
            out[(size_t)(id0 * NF + f) * P_HI + p] = a0 + bhc;
            out[(size_t)(id1 * NF + f) * P_HI + p] = a1 + bhc;
            out[(size_t)(id2 * NF + f) * P_HI + p] = a2 + bhc;
            out[(size_t)(id3 * NF + f) * P_HI + p] = a3 + bhc;

            // 5. fold next-f bias (its loads had the whole gather to land)
            if (fb) {
                float t = bhn;
                #pragma unroll
                for (int k = 0; k < KNN; ++k) t = fmaf(-wn[k], blg[k], t);
                bhn = t;
            }

            // 6. phase boundary: allow the 4 stores to stay in flight
            if (!last) {
                asm volatile("s_waitcnt vmcnt(4) lgkmcnt(0)" ::: "memory");
                __builtin_amdgcn_s_barrier();
                cur ^= 1;
                id0 = n0; id1 = n1; id2 = n2; id3 = n3;
                if (fb) {
                    #pragma unroll
                    for (int k = 0; k < KNN; ++k) w[k] = wn[k];
                    bhc = bhn;
                }
            }
        }
    }
}

extern "C" void kernel_launch(void* const* d_in, const int* in_sizes, int n_in,
                              void* d_out, int out_size, void* d_ws, size_t ws_size,
                              hipStream_t stream) {
    const float* x    = (const float*)d_in[0];
    const int*   cls  = (const int*)d_in[1];
    const int*   nbr  = (const int*)d_in[2];
    const float* wmap = (const float*)d_in[3];
    const float* blo  = (const float*)d_in[4];
    const float* bhi  = (const float*)d_in[5];
    float*       out  = (float*)d_out;
    int*         wsl  = (int*)d_ws;   // needs (64 + 36*128)*4 = 18.7 KB

    build_lists_kernel<<<1, 128, 0, stream>>>(cls, wsl);
    rect_up_kernel<<<NC * NTILES, THREADS, 0, stream>>>(
        x, wsl, nbr, wmap, blo, bhi, out);
}

// Round 9
// 163.515 us; speedup vs baseline: 1.0190x; 1.0190x over previous
//
#include <hip/hip_runtime.h>

#define BS      128
#define NF      4
#define NC      36
#define P_LO    1024
#define P_HI    16384
#define KNN     9
#define THREADS 256
#define TILE_P  256
#define NTILES  (P_HI / TILE_P)     // 64
#define LIST_OFF 64                 // ints; ws[0..35]=counts, ws[64+c*128+i]=sample ids
#define SCHED_OFF 36                // 9 ints = 36 packed bytes: rank -> class (LPT order)
#define SLICE   192                 // 6 lo rows x 32 cols: covers the 9-NN row span
                                    // [m-2, m+3] incl. all tie-shell anomalies
                                    // (d2=90 -> m+3; d2=130 -> m-2; verified exhaustively)

// ---- pre-pass: bucket samples by class; also LPT schedule (count desc) ----
__global__ __launch_bounds__(128) void build_lists_kernel(
    const int* __restrict__ cls_ids, int* __restrict__ ws)
{
    __shared__ int cnt[NC];
    __shared__ int pk[9];
    const int t = threadIdx.x;
    if (t < NC) cnt[t] = 0;
    if (t >= 64 && t < 73) pk[t - 64] = 0;
    __syncthreads();
    if (t < BS) {
        int c = cls_ids[t];
        int pos = atomicAdd(&cnt[c], 1);
        ws[LIST_OFF + c * BS + pos] = t;
    }
    __syncthreads();
    if (t < NC) {
        int ct = cnt[t];
        ws[t] = ct;
        int r = 0;                       // rank by (count desc, idx asc) -> bijective
        for (int j = 0; j < NC; ++j) {
            int cj = cnt[j];
            r += (cj > ct) || (cj == ct && j < t);
        }
        atomicOr(&pk[r >> 2], t << ((r & 3) << 3));
    }
    __syncthreads();
    if (t < 9) ws[SCHED_OFF + t] = pk[t];
}

// ---- main: block = (cls, tile of 2 hi rows); phases over (f, round) ----
// All operands register-direct (no DMA, no staging, no vmcnt waits at all).
// Bias folded: out = sum_k w_k*x[nb_k] + (bh - sum_k w_k*bl[nb_k]).
// Only the x slice lives in LDS: 6 lo rows x 32 cols x 4 samples, interleaved
// [192][4], double-buffered = 6144 B -> 8 blocks/CU (thread-capped).
// x pipeline: prologue fills phases 0..3 into {ybuf, xp1, xp2, xp3}; the
// in-loop load at phase ph targets phase ph+4 (NOT ph+3 — round-8 bug: loading
// ph+3 re-read a held phase and shifted every later phase's data by one).
__global__ __launch_bounds__(THREADS) void rect_up_kernel(
    const float* __restrict__ x,       // (BS, NF*P_LO)
    const int*   __restrict__ ws,      // counts + schedule + lists
    const int*   __restrict__ nbr,     // (P_HI, K)
    const float* __restrict__ wmap,    // (NC, NF, P_HI, K)
    const float* __restrict__ blo,     // (NC, NF, P_LO)
    const float* __restrict__ bhi,     // (NC, NF, P_HI)
    float*       __restrict__ out)     // (BS, NF, P_HI)
{
    __shared__ __align__(16) float ybuf[2][SLICE][4];   // 6144 B

    const int tile = blockIdx.x & (NTILES - 1);
    const int rank = blockIdx.x >> 6;
    const int cls  = (ws[SCHED_OFF + (rank >> 2)] >> ((rank & 3) << 3)) & 0xFF;
    const int n_b  = ws[cls];
    if (n_b == 0) return;              // uniform exit, before any barrier

    const int tid = threadIdx.x;
    const int p   = tile * TILE_P + tid;
    const int m   = tile >> 1;         // lo-row anchor of this tile's 2 hi rows
    const int base32 = (min(max(m - 2, 0), 26)) << 5;   // slice = rows [b, b+5]
    const int s   = tid >> 6;          // wave = sample slot (uniform per wave)
    const int qq  = tid & 63;          // 3 floats/thread within the 192-slice

    const int* list = ws + LIST_OFF + cls * BS;
    const int R  = (n_b + 3) >> 2;     // rounds of 4 samples per f
    const int NP = NF * R;             // total phases (>= 4)

    // per-wave sample id for round rr (clamp to round's first id; 4*rr < n_b)
#define WAVE_ID(rr) ((4 * (rr) + s < n_b) ? list[4 * (rr) + s] : list[4 * (rr)])
    // 3 coalesced floats of sample (ff,rr)'s slice: offsets qq, qq+64, qq+128
#define LOAD_XP(dst, ff, rr) {                                               \
        const int id_ = WAVE_ID(rr);                                         \
        const float* xp_ = x + ((size_t)id_ * NF + (ff)) * P_LO + base32 + qq; \
        dst[0] = xp_[0]; dst[1] = xp_[64]; dst[2] = xp_[128]; }

    // ---- prologue: one latency group of independent register loads ----
    int nbl[KNN];                      // neighbor indices rebased to the slice
    {
        const int* ir = nbr + (size_t)p * KNN;
        #pragma unroll
        for (int k = 0; k < KNN; ++k) nbl[k] = ir[k] - base32;
    }
    float w_[KNN];
    {
        const float* wr = wmap + ((size_t)cls * NF * P_HI + p) * KNN;   // f=0
        #pragma unroll
        for (int k = 0; k < KNN; ++k) w_[k] = wr[k];
    }
    float bhc;                         // folded bias for current f
    {
        float t = bhi[(size_t)cls * NF * P_HI + p];
        const float* blp = blo + (size_t)cls * NF * P_LO + base32;
        #pragma unroll
        for (int k = 0; k < KNN; ++k) t = fmaf(-w_[k], blp[nbl[k]], t);
        bhc = t;
    }

    // fill the x pipeline: phase 0 -> ybuf[0]; phases 1..3 -> registers
    float xp1[3], xp2[3], xp3[3];
    {
        float x0[3];
        LOAD_XP(x0, 0, 0);
        LOAD_XP(xp1, 1 / R, 1 % R);
        LOAD_XP(xp2, 2 / R, 2 % R);
        LOAD_XP(xp3, 3 / R, 3 % R);
        #pragma unroll
        for (int t = 0; t < 3; ++t) ybuf[0][qq + 64 * t][s] = x0[t];
    }
    asm volatile("s_waitcnt lgkmcnt(0)" ::: "memory");
    __builtin_amdgcn_s_barrier();      // ybuf[0] ready

    int pb = 0, f = 0, r = 0;
    int f3 = 4 / R, r3 = 4 % R;        // (f,r) of phase ph+4 (first in-loop load)
    float wn[KNN], bhn = 0.f;

    for (int ph = 0; ph < NP; ++ph) {
        // this round's 4 store ids (uniform scalar loads)
        const int s0  = 4 * r;
        const int id0 = list[s0];
        const int id1 = (s0 + 1 < n_b) ? list[s0 + 1] : id0;
        const int id2 = (s0 + 2 < n_b) ? list[s0 + 2] : id0;
        const int id3 = (s0 + 3 < n_b) ? list[s0 + 3] : id0;

        // 1. write phase ph+1's planes (xp1 loaded 3 phases ago)
        if (ph + 1 < NP) {
            #pragma unroll
            for (int t = 0; t < 3; ++t) ybuf[pb ^ 1][qq + 64 * t][s] = xp1[t];
        }

        // 2. rotate pipeline; issue loads for phase ph+4
        #pragma unroll
        for (int t = 0; t < 3; ++t) { xp1[t] = xp2[t]; xp2[t] = xp3[t]; }
        if (f3 < NF) LOAD_XP(xp3, f3, r3);

        // 3. once per f: issue next-f w row + bias-gather (folded in step 6,
        //    so these loads have the whole gather to land)
        float blgn[KNN];
        const bool fb = (r == 0) && (f + 1 < NF);
        if (fb) {
            const float* wrn = wmap + ((size_t)(cls * NF + f + 1) * P_HI + p) * KNN;
            #pragma unroll
            for (int k = 0; k < KNN; ++k) wn[k] = wrn[k];
            const float* blpn = blo + (size_t)(cls * NF + f + 1) * P_LO + base32;
            #pragma unroll
            for (int k = 0; k < KNN; ++k) blgn[k] = blpn[nbl[k]];
            bhn = bhi[(size_t)(cls * NF + f + 1) * P_HI + p];
        }

        // 4. gather: one ds_read_b128 per neighbor feeds 4 samples' FMAs
        const float* yb = &ybuf[pb][0][0];
        float a0 = 0.f, a1 = 0.f, a2 = 0.f, a3 = 0.f;
        #pragma unroll
        for (int k = 0; k < KNN; ++k) {
            const float4 yv = *(const float4*)(yb + 4 * nbl[k]);
            a0 = fmaf(w_[k], yv.x, a0);
            a1 = fmaf(w_[k], yv.y, a1);
            a2 = fmaf(w_[k], yv.z, a2);
            a3 = fmaf(w_[k], yv.w, a3);
        }

        // 5. unconditional stores (clamped duplicate ids write identical values)
        out[((size_t)id0 * NF + f) * P_HI + p] = a0 + bhc;
        out[((size_t)id1 * NF + f) * P_HI + p] = a1 + bhc;
        out[((size_t)id2 * NF + f) * P_HI + p] = a2 + bhc;
        out[((size_t)id3 * NF + f) * P_HI + p] = a3 + bhc;

        // 6. fold next-f bias
        if (fb) {
            float t = bhn;
            #pragma unroll
            for (int k = 0; k < KNN; ++k) t = fmaf(-wn[k], blgn[k], t);
            bhn = t;
        }

        // 7. phase boundary: LDS-ordering only; stores/prefetches stay in flight
        if (ph + 1 < NP) {
            asm volatile("s_waitcnt lgkmcnt(0)" ::: "memory");
            __builtin_amdgcn_s_barrier();
        }
        pb ^= 1;
        if (++r == R) {                // f boundary: promote next-f operands
            r = 0; ++f;
            #pragma unroll
            for (int k = 0; k < KNN; ++k) w_[k] = wn[k];
            bhc = bhn;
        }
        if (++r3 == R) { r3 = 0; ++f3; }
    }
#undef LOAD_XP
#undef WAVE_ID
}

extern "C" void kernel_launch(void* const* d_in, const int* in_sizes, int n_in,
                              void* d_out, int out_size, void* d_ws, size_t ws_size,
                              hipStream_t stream) {
    const float* x    = (const float*)d_in[0];
    const int*   cls  = (const int*)d_in[1];
    const int*   nbr  = (const int*)d_in[2];
    const float* wmap = (const float*)d_in[3];
    const float* blo  = (const float*)d_in[4];
    const float* bhi  = (const float*)d_in[5];
    float*       out  = (float*)d_out;
    int*         wsl  = (int*)d_ws;   // needs (64 + 36*128)*4 = 18.7 KB

    build_lists_kernel<<<1, 128, 0, stream>>>(cls, wsl);
    rect_up_kernel<<<NC * NTILES, THREADS, 0, stream>>>(
        x, wsl, nbr, wmap, blo, bhi, out);
}

// Round 10
// 163.215 us; speedup vs baseline: 1.0209x; 1.0018x over previous
//
#include <hip/hip_runtime.h>

#define BS      128
#define NF      4
#define NC      36
#define P_LO    1024
#define P_HI    16384
#define KNN     9
#define THREADS 256
#define WTILE   64                  // hi positions per WAVE (1 per lane)
#define NTILES  (P_HI / WTILE)      // 256 tiles per (cls, f)
#define LIST_OFF 64                 // ints; ws[0..35]=counts, ws[64+c*128+i]=sample ids
#define SCHED_OFF 36                // 9 ints = 36 packed bytes: rank -> class (LPT order)
#define SLICE   192                 // 6 lo rows x 32 cols: covers the 9-NN row span
                                    // [m-2, m+3] incl. all tie-shell anomalies (verified)

// ---- pre-pass: bucket samples by class; also LPT schedule (count desc) ----
__global__ __launch_bounds__(128) void build_lists_kernel(
    const int* __restrict__ cls_ids, int* __restrict__ ws)
{
    __shared__ int cnt[NC];
    __shared__ int pk[9];
    const int t = threadIdx.x;
    if (t < NC) cnt[t] = 0;
    if (t >= 64 && t < 73) pk[t - 64] = 0;
    __syncthreads();
    if (t < BS) {
        int c = cls_ids[t];
        int pos = atomicAdd(&cnt[c], 1);
        ws[LIST_OFF + c * BS + pos] = t;
    }
    __syncthreads();
    if (t < NC) {
        int ct = cnt[t];
        ws[t] = ct;
        int r = 0;                       // rank by (count desc, idx asc) -> bijective
        for (int j = 0; j < NC; ++j) {
            int cj = cnt[j];
            r += (cj > ct) || (cj == ct && j < t);
        }
        atomicOr(&pk[r >> 2], t << ((r & 3) << 3));
    }
    __syncthreads();
    if (t < 9) ws[SCHED_OFF + t] = pk[t];
}

// ---- main: ONE WAVE = one (cls, f, 64-position tile); ZERO barriers ----
// Theory: all prior variants (44-52us) were MLP-bound by s_barrier phase-
// locking (whole block's VMEM queue drains at each phase edge). Here the
// x slice is WAVE-PRIVATE in LDS, so ds_write -> ds_read ordering needs only
// lgkmcnt (DS pipe is per-wave in-order); no s_barrier exists in the kernel.
// Waves free-run: prologue chain + 1-deep x prefetch + stores never drained.
// Bias folded: out = sum_k w_k*x[nb_k] + (bh - sum_k w_k*bl[nb_k]).
__global__ __launch_bounds__(THREADS) void rect_up_kernel(
    const float* __restrict__ x,       // (BS, NF*P_LO)
    const int*   __restrict__ ws,      // counts + schedule + lists
    const int*   __restrict__ nbr,     // (P_HI, K)
    const float* __restrict__ wmap,    // (NC, NF, P_HI, K)
    const float* __restrict__ blo,     // (NC, NF, P_LO)
    const float* __restrict__ bhi,     // (NC, NF, P_HI)
    float*       __restrict__ out)     // (BS, NF, P_HI)
{
    __shared__ __align__(16) float ybuf[4][SLICE][4];   // 12288 B, row per wave

    const int tid  = threadIdx.x;
    const int wv   = tid >> 6;
    const int lane = tid & 63;
    const int u    = (blockIdx.x << 2) | wv;   // wave-unit id, 0..36863
    const int tile = u & (NTILES - 1);         // varies fastest -> contiguous wmap
    const int fr   = u >> 8;                   // 0..143: (rank, f)
    const int f    = fr & (NF - 1);
    const int rank = fr >> 2;
    const int cls  = (ws[SCHED_OFF + (rank >> 2)] >> ((rank & 3) << 3)) & 0xFF;
    const int n_b  = ws[cls];
    if (n_b == 0) return;                      // no barriers -> safe per-wave exit

    const int p      = tile * WTILE + lane;    // hi position; hi row = p>>7
    const int m      = p >> 9;                 // lo-row anchor = (p>>7)>>2
    const int base32 = min(max(m - 2, 0), 26) << 5;   // slice rows [b, b+5]

    const int* list = ws + LIST_OFF + cls * BS;
    const int R = (n_b + 3) >> 2;              // rounds of 4 samples

    // ---- prologue: one latency group of independent register loads ----
    int nbl[KNN];                              // neighbor idx rebased to slice
    {
        const int* ir = nbr + (size_t)p * KNN;
        #pragma unroll
        for (int k = 0; k < KNN; ++k) nbl[k] = ir[k] - base32;
    }
    float w_[KNN];
    {
        const float* wr = wmap + ((size_t)(cls * NF + f) * P_HI + p) * KNN;
        #pragma unroll
        for (int k = 0; k < KNN; ++k) w_[k] = wr[k];
    }
    float bhc = bhi[(size_t)(cls * NF + f) * P_HI + p];
    {
        const float* blp = blo + (size_t)(cls * NF + f) * P_LO + base32;
        #pragma unroll
        for (int k = 0; k < KNN; ++k) bhc = fmaf(-w_[k], blp[nbl[k]], bhc);
    }

    int id0 = list[0];
    int id1 = (1 < n_b) ? list[1] : id0;
    int id2 = (2 < n_b) ? list[2] : id0;
    int id3 = (3 < n_b) ? list[3] : id0;

    // round-0 x slice: 12 fully-coalesced dword loads (256 B/wave each)
    float xv[12];                              // xv[s*3 + t]
    {
        const float* b0 = x + ((size_t)id0 * NF + f) * P_LO + base32 + lane;
        const float* b1 = x + ((size_t)id1 * NF + f) * P_LO + base32 + lane;
        const float* b2 = x + ((size_t)id2 * NF + f) * P_LO + base32 + lane;
        const float* b3 = x + ((size_t)id3 * NF + f) * P_LO + base32 + lane;
        #pragma unroll
        for (int t = 0; t < 3; ++t) {
            xv[t]     = b0[t << 6];
            xv[3 + t] = b1[t << 6];
            xv[6 + t] = b2[t << 6];
            xv[9 + t] = b3[t << 6];
        }
    }

    for (int r = 0; r < R; ++r) {
        // WAR guard: prior round's ds_reads completed (results in regs) before
        // overwriting the slice. lgkm-only; no barrier. ~free (reads consumed).
        if (r) asm volatile("s_waitcnt lgkmcnt(0)" ::: "memory");

        // write the 4 sample-planes, interleaved [192][4]: 3x ds_write_b128
        #pragma unroll
        for (int t = 0; t < 3; ++t) {
            float4 v;
            v.x = xv[t]; v.y = xv[3 + t]; v.z = xv[6 + t]; v.w = xv[9 + t];
            *(float4*)&ybuf[wv][lane + (t << 6)][0] = v;
        }

        const int c0 = id0, c1 = id1, c2 = id2, c3 = id3;

        // prefetch next round's ids + x (issues before the gather; latency
        // hides under ds_reads + FMAs and across free-running waves)
        float xn[12];
        if (r + 1 < R) {
            const int s = 4 * (r + 1);
            id0 = list[s];
            id1 = (s + 1 < n_b) ? list[s + 1] : id0;
            id2 = (s + 2 < n_b) ? list[s + 2] : id0;
            id3 = (s + 3 < n_b) ? list[s + 3] : id0;
            const float* b0 = x + ((size_t)id0 * NF + f) * P_LO + base32 + lane;
            const float* b1 = x + ((size_t)id1 * NF + f) * P_LO + base32 + lane;
            const float* b2 = x + ((size_t)id2 * NF + f) * P_LO + base32 + lane;
            const float* b3 = x + ((size_t)id3 * NF + f) * P_LO + base32 + lane;
            #pragma unroll
            for (int t = 0; t < 3; ++t) {
                xn[t]     = b0[t << 6];
                xn[3 + t] = b1[t << 6];
                xn[6 + t] = b2[t << 6];
                xn[9 + t] = b3[t << 6];
            }
        }

        // gather: one ds_read_b128 per neighbor feeds 4 samples' FMAs
        // (compiler inserts the lgkmcnt wait for the write->read dependency)
        const float* yb = &ybuf[wv][0][0];
        float a0 = 0.f, a1 = 0.f, a2 = 0.f, a3 = 0.f;
        #pragma unroll
        for (int k = 0; k < KNN; ++k) {
            const float4 yv = *(const float4*)(yb + (nbl[k] << 2));
            a0 = fmaf(w_[k], yv.x, a0);
            a1 = fmaf(w_[k], yv.y, a1);
            a2 = fmaf(w_[k], yv.z, a2);
            a3 = fmaf(w_[k], yv.w, a3);
        }

        // unconditional stores (clamped duplicate ids write identical values);
        // never waited on -> ride across rounds and wave exit
        out[((size_t)c0 * NF + f) * P_HI + p] = a0 + bhc;
        out[((size_t)c1 * NF + f) * P_HI + p] = a1 + bhc;
        out[((size_t)c2 * NF + f) * P_HI + p] = a2 + bhc;
        out[((size_t)c3 * NF + f) * P_HI + p] = a3 + bhc;

        if (r + 1 < R) {
            #pragma unroll
            for (int t = 0; t < 12; ++t) xv[t] = xn[t];
        }
    }
}

extern "C" void kernel_launch(void* const* d_in, const int* in_sizes, int n_in,
                              void* d_out, int out_size, void* d_ws, size_t ws_size,
                              hipStream_t stream) {
    const float* x    = (const float*)d_in[0];
    const int*   cls  = (const int*)d_in[1];
    const int*   nbr  = (const int*)d_in[2];
    const float* wmap = (const float*)d_in[3];
    const float* blo  = (const float*)d_in[4];
    const float* bhi  = (const float*)d_in[5];
    float*       out  = (float*)d_out;
    int*         wsl  = (int*)d_ws;   // needs (64 + 36*128)*4 = 18.7 KB

    build_lists_kernel<<<1, 128, 0, stream>>>(cls, wsl);
    rect_up_kernel<<<NC * NF * NTILES / 4, THREADS, 0, stream>>>(
        x, wsl, nbr, wmap, blo, bhi, out);
}